// Round 4
// baseline (270.907 us; speedup 1.0000x reference)
//
#include <hip/hip_runtime.h>

// DiffuseLR zero-device-atomic pipeline v2:
//   partition edges by src-bucket (counting sort, LDS-only atomics), then
//   gather-fold g[s,c] = sum_{e:src=s} wn_e*fc_w[c,dst_e] (+ self-loop),
//   then logits = x @ gT + b, softmax.

#define N_NODES   20000
#define N_EDGES_C 640000
#define N_CLASSES 30
#define BATCH_C   128
#define CPAD      32

// deg-hist geometry
#define HBLKS     64
#define HNODES    10000
#define HEDGES    (N_EDGES_C / HBLKS)     // 10000

// partition geometry
#define BN        128                     // nodes per bucket
#define NBUCKET   157                     // ceil(20000/128)
#define NPB       (NBUCKET * BN)          // 20096 padded nodes
#define NSLAB     256
#define SLAB_E    (N_EDGES_C / NSLAB)     // 2500
#define NSCAN     (NBUCKET * NSLAB)       // 40192
#define FSLICE    4

// gemm geometry
#define NCHUNK7   128
#define NCHUNKS7  157
#define XL_LD     130
#define GT_LD     132

// K1: weighted in-degree histogram (LDS), per (edge-slab, node-half)
__global__ __launch_bounds__(256) void hist_kernel(const int* __restrict__ dst,
        const float* __restrict__ w, float* __restrict__ degp) {
    __shared__ float h[HNODES];
    int eb = blockIdx.x, half = blockIdx.y;
    int nbase = half * HNODES;
    for (int i = threadIdx.x; i < HNODES; i += 256) h[i] = 0.f;
    __syncthreads();
    int e0 = eb * HEDGES;
    for (int i = threadIdx.x; i < HEDGES; i += 256) {
        int d = dst[e0 + i];
        unsigned r = (unsigned)(d - nbase);
        if (r < HNODES) atomicAdd(&h[r], w[e0 + i]);
    }
    __syncthreads();
    float* outp = degp + (size_t)(eb * 2 + half) * HNODES;
    for (int i = threadIdx.x; i < HNODES; i += 256) outp[i] = h[i];
}

// K2: bucket counts per slab (LDS histogram, no device atomics)
__global__ __launch_bounds__(256) void histb_kernel(const int* __restrict__ src,
        int* __restrict__ cnt) {
    __shared__ int bc[NBUCKET];
    int slab = blockIdx.x;
    for (int i = threadIdx.x; i < NBUCKET; i += 256) bc[i] = 0;
    __syncthreads();
    const int4* s4 = (const int4*)(src + slab * SLAB_E);
    for (int i = threadIdx.x; i < SLAB_E / 4; i += 256) {
        int4 v = s4[i];
        atomicAdd(&bc[v.x >> 7], 1);
        atomicAdd(&bc[v.y >> 7], 1);
        atomicAdd(&bc[v.z >> 7], 1);
        atomicAdd(&bc[v.w >> 7], 1);
    }
    __syncthreads();
    for (int b = threadIdx.x; b < NBUCKET; b += 256) cnt[b * NSLAB + slab] = bc[b];
}

// K3: fc_wT[20096][32] transpose-pad  +  dinv = rsqrt(1 + deg)  (merged)
__global__ __launch_bounds__(256) void prep_kernel(const float* __restrict__ fc_w,
        const float* __restrict__ degp, float* __restrict__ fc_wT,
        float* __restrict__ dinv) {
    int bid = blockIdx.x;
    if (bid < (NPB * CPAD) / 256) {
        int idx = bid * 256 + threadIdx.x;
        int n = idx >> 5, c = idx & 31;
        fc_wT[idx] = (c < N_CLASSES && n < N_NODES) ? fc_w[c * N_NODES + n] : 0.f;
    } else {
        int n = (bid - (NPB * CPAD) / 256) * 256 + threadIdx.x;
        if (n < N_NODES) {
            int half = n / HNODES, nn = n % HNODES;
            float s = 1.0f;  // self-loop weight
            for (int eb = 0; eb < HBLKS; eb++)
                s += degp[(size_t)(eb * 2 + half) * HNODES + nn];
            dinv[n] = rsqrtf(s);
        }
    }
}

// K4: exclusive scan of cnt[NSCAN] -> off[NSCAN+1] (single block)
__global__ __launch_bounds__(1024) void scan_kernel(const int* __restrict__ cnt,
        int* __restrict__ off) {
    __shared__ int partial[1024];
    int t = threadIdx.x;
    int i0 = t * 40;
    int vals[40];
    int sum = 0;
    #pragma unroll
    for (int j = 0; j < 40; j++) {
        int i = i0 + j;
        int v = (i < NSCAN) ? cnt[i] : 0;
        vals[j] = v; sum += v;
    }
    partial[t] = sum;
    __syncthreads();
    for (int o = 1; o < 1024; o <<= 1) {
        int v = (t >= o) ? partial[t - o] : 0;
        __syncthreads();
        partial[t] += v;
        __syncthreads();
    }
    int base = (t > 0) ? partial[t - 1] : 0;
    #pragma unroll
    for (int j = 0; j < 40; j++) {
        int i = i0 + j;
        if (i <= NSCAN) off[i] = base;
        base += vals[j];
    }
}

// K5: scatter edges into bucket-partitioned records {(s_local<<15)|d, wn}
__global__ __launch_bounds__(256) void scatter_kernel(const int* __restrict__ src,
        const int* __restrict__ dst, const float* __restrict__ w,
        const float* __restrict__ dinv, const int* __restrict__ off,
        int2* __restrict__ erec) {
    __shared__ int cur[NBUCKET];
    int slab = blockIdx.x;
    for (int b = threadIdx.x; b < NBUCKET; b += 256) cur[b] = off[b * NSLAB + slab];
    __syncthreads();
    int e0 = slab * SLAB_E;
    const int4* s4 = (const int4*)(src + e0);
    const int4* d4 = (const int4*)(dst + e0);
    const float4* w4 = (const float4*)(w + e0);
    for (int i = threadIdx.x; i < SLAB_E / 4; i += 256) {
        int4 sv = s4[i]; int4 dv = d4[i]; float4 wv = w4[i];
        int s, d, p; float wn;
        s = sv.x; d = dv.x; wn = dinv[s] * wv.x * dinv[d];
        p = atomicAdd(&cur[s >> 7], 1);
        erec[p] = make_int2(((s & 127) << 15) | d, __float_as_int(wn));
        s = sv.y; d = dv.y; wn = dinv[s] * wv.y * dinv[d];
        p = atomicAdd(&cur[s >> 7], 1);
        erec[p] = make_int2(((s & 127) << 15) | d, __float_as_int(wn));
        s = sv.z; d = dv.z; wn = dinv[s] * wv.z * dinv[d];
        p = atomicAdd(&cur[s >> 7], 1);
        erec[p] = make_int2(((s & 127) << 15) | d, __float_as_int(wn));
        s = sv.w; d = dv.w; wn = dinv[s] * wv.w * dinv[d];
        p = atomicAdd(&cur[s >> 7], 1);
        erec[p] = make_int2(((s & 127) << 15) | d, __float_as_int(wn));
    }
}

// K6: gather-fold. Block (bucket, slice): 32-lane group per edge, lane = class.
// LDS atomics are lane->bank conflict-free (2 groups/wave = 2-way = free).
__global__ __launch_bounds__(512) void fold_kernel(const int2* __restrict__ erec,
        const int* __restrict__ off, const float* __restrict__ dinv,
        const float* __restrict__ fc_wT, float* __restrict__ g_part) {
    __shared__ float gl[BN * CPAD];   // 16 KB
    int bucket = blockIdx.x, slice = blockIdx.y;
    int nlo = bucket * BN;
    for (int i = threadIdx.x; i < BN * CPAD; i += 512) gl[i] = 0.f;
    __syncthreads();
    int bstart = off[bucket * NSLAB];
    int bend   = off[(bucket + 1) * NSLAB];
    int len = bend - bstart;
    int s0 = bstart + (len * slice) / FSLICE;
    int s1 = bstart + (len * (slice + 1)) / FSLICE;
    int grp = threadIdx.x >> 5, c = threadIdx.x & 31;
    for (int i = s0 + grp; i < s1; i += 16) {
        int2 r = erec[i];                       // wave-uniform per group: broadcast
        int d  = r.x & 0x7FFF;
        int sl = r.x >> 15;
        float wn = __int_as_float(r.y);
        atomicAdd(&gl[sl * CPAD + c], wn * fc_wT[d * CPAD + c]);
    }
    if (slice == FSLICE - 1) {                   // self-loops, lane = class
        for (int i = grp; i < BN; i += 16) {
            int n = nlo + i;
            if (n < N_NODES) {
                float di = dinv[n];
                atomicAdd(&gl[i * CPAD + c], di * di * fc_wT[n * CPAD + c]);
            }
        }
    }
    __syncthreads();
    float* outp = g_part + ((size_t)slice * NPB + nlo) * CPAD;
    for (int i = threadIdx.x; i < BN * CPAD; i += 512) outp[i] = gl[i];
}

// K7: logits partials; slice-reduction of g_part folded into the gt stage.
__global__ __launch_bounds__(512) void gemm_kernel(const float* __restrict__ x,
        const float* __restrict__ g_part, float* __restrict__ part) {
    __shared__ float xl[64 * XL_LD];      // 33.3 KB
    __shared__ float gt[CPAD * GT_LD];    // 16.9 KB
    int ch = blockIdx.x, bh = blockIdx.y;
    int n0 = ch * NCHUNK7;
    int b0 = bh * 64;
    for (int o = threadIdx.x; o < 64 * NCHUNK7; o += 512) {
        int b = o >> 7, n = o & 127;
        int gn = n0 + n;
        float v = (gn < N_NODES) ? x[(size_t)(b0 + b) * N_NODES + gn] : 0.f;
        xl[(n >> 1) * XL_LD + b * 2 + (n & 1)] = v;
    }
    for (int o = threadIdx.x; o < NCHUNK7 * CPAD; o += 512) {
        int n = o >> 5, c = o & 31;
        float s = 0.f;
        #pragma unroll
        for (int sl = 0; sl < FSLICE; sl++)
            s += g_part[(size_t)sl * NPB * CPAD + (size_t)n0 * CPAD + o];
        gt[c * GT_LD + n] = s;
    }
    __syncthreads();
    int wv = threadIdx.x >> 6, l = threadIdx.x & 63;
    float acc0 = 0.f, acc1 = 0.f, acc2 = 0.f, acc3 = 0.f;
    #pragma unroll 4
    for (int n4 = 0; n4 < NCHUNK7 / 4; n4++) {
        float2 xa = *(const float2*)&xl[(2 * n4) * XL_LD + l * 2];
        float2 xb = *(const float2*)&xl[(2 * n4 + 1) * XL_LD + l * 2];
        float4 ga = *(const float4*)&gt[(wv)      * GT_LD + 4 * n4];
        float4 gb = *(const float4*)&gt[(wv +  8) * GT_LD + 4 * n4];
        float4 gc = *(const float4*)&gt[(wv + 16) * GT_LD + 4 * n4];
        float4 gd = *(const float4*)&gt[(wv + 24) * GT_LD + 4 * n4];
        acc0 += xa.x * ga.x + xa.y * ga.y + xb.x * ga.z + xb.y * ga.w;
        acc1 += xa.x * gb.x + xa.y * gb.y + xb.x * gb.z + xb.y * gb.w;
        acc2 += xa.x * gc.x + xa.y * gc.y + xb.x * gc.z + xb.y * gc.w;
        acc3 += xa.x * gd.x + xa.y * gd.y + xb.x * gd.z + xb.y * gd.w;
    }
    size_t pb = (size_t)(ch * 2 + bh) * CPAD * 64;
    part[pb + (size_t)(wv)      * 64 + l] = acc0;
    part[pb + (size_t)(wv +  8) * 64 + l] = acc1;
    part[pb + (size_t)(wv + 16) * 64 + l] = acc2;
    part[pb + (size_t)(wv + 24) * 64 + l] = acc3;
}

// K8: logits[b][c] = sum over chunks + bias
__global__ __launch_bounds__(256) void lred_kernel(const float* __restrict__ part,
        const float* __restrict__ fc_b, float* __restrict__ logits_g) {
    __shared__ float lds[256];
    int c = blockIdx.x;
    int b = threadIdx.x & 127;
    int g2 = threadIdx.x >> 7;
    int bhl = b >> 6, l = b & 63;
    float s = 0.f;
    for (int ch = g2; ch < NCHUNKS7; ch += 2)
        s += part[((size_t)(ch * 2 + bhl) * CPAD + c) * 64 + l];
    lds[threadIdx.x] = s;
    __syncthreads();
    if (g2 == 0)
        logits_g[b * CPAD + c] = lds[b] + lds[b + 128] + fc_b[c];
}

// K9: softmax
__global__ void smax_kernel(const float* __restrict__ logits_g, float* __restrict__ out) {
    int b = threadIdx.x;
    float v[N_CLASSES], m = -1e30f;
    #pragma unroll
    for (int c = 0; c < N_CLASSES; c++) { v[c] = logits_g[b * CPAD + c]; m = fmaxf(m, v[c]); }
    float s = 0.f;
    #pragma unroll
    for (int c = 0; c < N_CLASSES; c++) { v[c] = __expf(v[c] - m); s += v[c]; }
    float inv = 1.0f / s;
    #pragma unroll
    for (int c = 0; c < N_CLASSES; c++) out[b * N_CLASSES + c] = v[c] * inv;
}

extern "C" void kernel_launch(void* const* d_in, const int* in_sizes, int n_in,
                              void* d_out, int out_size, void* d_ws, size_t ws_size,
                              hipStream_t stream) {
    const float* x          = (const float*)d_in[0];
    const int*   edge_index = (const int*)d_in[1];
    const float* ew         = (const float*)d_in[2];
    const float* fc_w       = (const float*)d_in[3];
    const float* fc_b       = (const float*)d_in[4];
    float* out = (float*)d_out;

    const int* src = edge_index;
    const int* dst = edge_index + N_EDGES_C;

    // ws layout (floats), time-disjoint aliasing:
    //   A (2,572,288): degp [K1..K3]  ->  g_part [K6..K7]
    //   B (1,280,000): erec [K5..K6]  ->  part   [K7..K8]
    float* A        = (float*)d_ws;                          // 2,572,288
    float* B        = A + (size_t)FSLICE * NPB * CPAD;       // 1,280,000
    float* dinv     = B + 2 * (size_t)N_EDGES_C;             // 20,000
    int*   cnt      = (int*)(dinv + N_NODES);                // 40,192
    int*   off      = cnt + NSCAN;                           // 40,193 (pad 40,200)
    float* fc_wT    = (float*)(off + 40200);                 // 643,072
    float* logits_g = fc_wT + (size_t)NPB * CPAD;            // 4,096

    float* degp   = A;
    float* g_part = A;
    int2*  erec   = (int2*)B;
    float* part   = B;

    hist_kernel<<<dim3(HBLKS, 2), 256, 0, stream>>>(dst, ew, degp);
    histb_kernel<<<NSLAB, 256, 0, stream>>>(src, cnt);
    prep_kernel<<<(NPB * CPAD) / 256 + (N_NODES + 255) / 256, 256, 0, stream>>>(
        fc_w, degp, fc_wT, dinv);
    scan_kernel<<<1, 1024, 0, stream>>>(cnt, off);
    scatter_kernel<<<NSLAB, 256, 0, stream>>>(src, dst, ew, dinv, off, erec);
    fold_kernel<<<dim3(NBUCKET, FSLICE), 512, 0, stream>>>(erec, off, dinv, fc_wT, A);
    gemm_kernel<<<dim3(NCHUNKS7, 2), 512, 0, stream>>>(x, A, part);
    lred_kernel<<<N_CLASSES, 256, 0, stream>>>(part, fc_b, logits_g);
    smax_kernel<<<1, 128, 0, stream>>>(logits_g, out);
}

// Round 5
// 249.660 us; speedup vs baseline: 1.0851x; 1.0851x over previous
//
#include <hip/hip_runtime.h>

// DiffuseLR v3: counting-sort partition + batched gather-fold + split GEMM.
//   g[s,c] = sum_{e:src=s} wn_e*fc_w[c,dst_e] + dinv[s]^2*fc_w[c,s]
//   logits = x @ gT + b; out = softmax(logits)
// 7 launches, zero device atomics, zero memsets (all buffers fully written).

#define N_NODES   20000
#define N_EDGES_C 640000
#define N_CLASSES 30
#define CPAD      32

// deg-hist geometry
#define HBLKS     64
#define HNODES    10000
#define HEDGES    (N_EDGES_C / HBLKS)     // 10000

// partition geometry
#define BN        128
#define NBUCKET   157
#define NPB       (NBUCKET * BN)          // 20096
#define NSLAB     256
#define SLAB_E    (N_EDGES_C / NSLAB)     // 2500
#define NSCAN     (NBUCKET * NSLAB)       // 40192
#define FSLICE    4

// gemm geometry
#define NCHUNK    64
#define NCHUNKS   313                     // 313*64 = 20032 >= 20000
#define XL_LD     130
#define GT_LD     68

// L1: (a) blocks [0,128): weighted in-degree LDS histogram per (edge-slab, half)
//     (b) blocks [128,384): src-bucket counts per slab (for counting sort)
__global__ __launch_bounds__(256) void l1_hists(const int* __restrict__ src,
        const int* __restrict__ dst, const float* __restrict__ w,
        float* __restrict__ degp, int* __restrict__ cnt) {
    __shared__ float h[HNODES];   // 40 KB (aliased as int bc[] in role b)
    int bid = blockIdx.x;
    if (bid < 2 * HBLKS) {
        int eb = bid >> 1, half = bid & 1;
        int nbase = half * HNODES;
        for (int i = threadIdx.x; i < HNODES; i += 256) h[i] = 0.f;
        __syncthreads();
        const int4* d4 = (const int4*)(dst + eb * HEDGES);
        const float4* w4 = (const float4*)(w + eb * HEDGES);
        for (int i = threadIdx.x; i < HEDGES / 4; i += 256) {
            int4 dv = d4[i]; float4 wv = w4[i];
            unsigned r;
            r = (unsigned)(dv.x - nbase); if (r < HNODES) atomicAdd(&h[r], wv.x);
            r = (unsigned)(dv.y - nbase); if (r < HNODES) atomicAdd(&h[r], wv.y);
            r = (unsigned)(dv.z - nbase); if (r < HNODES) atomicAdd(&h[r], wv.z);
            r = (unsigned)(dv.w - nbase); if (r < HNODES) atomicAdd(&h[r], wv.w);
        }
        __syncthreads();
        float* outp = degp + (size_t)bid * HNODES;
        for (int i = threadIdx.x; i < HNODES; i += 256) outp[i] = h[i];
    } else {
        int slab = bid - 2 * HBLKS;
        int* bc = (int*)h;
        for (int i = threadIdx.x; i < NBUCKET; i += 256) bc[i] = 0;
        __syncthreads();
        const int4* s4 = (const int4*)(src + slab * SLAB_E);
        for (int i = threadIdx.x; i < SLAB_E / 4; i += 256) {
            int4 v = s4[i];
            atomicAdd(&bc[v.x >> 7], 1);
            atomicAdd(&bc[v.y >> 7], 1);
            atomicAdd(&bc[v.z >> 7], 1);
            atomicAdd(&bc[v.w >> 7], 1);
        }
        __syncthreads();
        for (int b = threadIdx.x; b < NBUCKET; b += 256) cnt[b * NSLAB + slab] = bc[b];
    }
}

// L2: block 0 = exclusive scan cnt->off; blocks [1,628] = fc_w transpose-pad;
//     blocks [629,648] = dinv = rsqrt(1 + deg). All independent of the scan.
__global__ __launch_bounds__(1024) void l2_prep(const int* __restrict__ cnt,
        int* __restrict__ off, const float* __restrict__ fc_w,
        const float* __restrict__ degp, float* __restrict__ fc_wT,
        float* __restrict__ dinv) {
    int bid = blockIdx.x;
    if (bid == 0) {
        __shared__ int partial[1024];
        int t = threadIdx.x;
        int i0 = t * 40;
        int vals[40];
        int sum = 0;
        #pragma unroll
        for (int j = 0; j < 40; j++) {
            int i = i0 + j;
            int v = (i < NSCAN) ? cnt[i] : 0;
            vals[j] = v; sum += v;
        }
        partial[t] = sum;
        __syncthreads();
        for (int o = 1; o < 1024; o <<= 1) {
            int v = (t >= o) ? partial[t - o] : 0;
            __syncthreads();
            partial[t] += v;
            __syncthreads();
        }
        int base = (t > 0) ? partial[t - 1] : 0;
        #pragma unroll
        for (int j = 0; j < 40; j++) {
            int i = i0 + j;
            if (i <= NSCAN) off[i] = base;
            base += vals[j];
        }
    } else if (bid <= (NPB * CPAD) / 1024) {       // 628 blocks
        int idx = (bid - 1) * 1024 + threadIdx.x;
        int n = idx >> 5, c = idx & 31;
        fc_wT[idx] = (c < N_CLASSES && n < N_NODES) ? fc_w[c * N_NODES + n] : 0.f;
    } else {
        int n = (bid - 1 - (NPB * CPAD) / 1024) * 1024 + threadIdx.x;
        if (n < N_NODES) {
            int half = n / HNODES, nn = n - half * HNODES;
            float s = 1.0f;   // self-loop weight
            for (int eb = 0; eb < HBLKS; eb++)
                s += degp[(size_t)((eb << 1) | half) * HNODES + nn];
            dinv[n] = rsqrtf(s);
        }
    }
}

// L3: scatter edges into bucket-partitioned records {(s_local<<15)|d, wn}
__global__ __launch_bounds__(512) void l3_scatter(const int* __restrict__ src,
        const int* __restrict__ dst, const float* __restrict__ w,
        const float* __restrict__ dinv, const int* __restrict__ off,
        int2* __restrict__ erec) {
    __shared__ int cur[NBUCKET];
    int slab = blockIdx.x;
    for (int b = threadIdx.x; b < NBUCKET; b += 512) cur[b] = off[b * NSLAB + slab];
    __syncthreads();
    int e0 = slab * SLAB_E;
    const int4* s4 = (const int4*)(src + e0);
    const int4* d4 = (const int4*)(dst + e0);
    const float4* w4 = (const float4*)(w + e0);
    for (int i = threadIdx.x; i < SLAB_E / 4; i += 512) {
        int4 sv = s4[i]; int4 dv = d4[i]; float4 wv = w4[i];
        int s, d, p; float wn;
        s = sv.x; d = dv.x; wn = dinv[s] * wv.x * dinv[d];
        p = atomicAdd(&cur[s >> 7], 1);
        erec[p] = make_int2(((s & 127) << 15) | d, __float_as_int(wn));
        s = sv.y; d = dv.y; wn = dinv[s] * wv.y * dinv[d];
        p = atomicAdd(&cur[s >> 7], 1);
        erec[p] = make_int2(((s & 127) << 15) | d, __float_as_int(wn));
        s = sv.z; d = dv.z; wn = dinv[s] * wv.z * dinv[d];
        p = atomicAdd(&cur[s >> 7], 1);
        erec[p] = make_int2(((s & 127) << 15) | d, __float_as_int(wn));
        s = sv.w; d = dv.w; wn = dinv[s] * wv.w * dinv[d];
        p = atomicAdd(&cur[s >> 7], 1);
        erec[p] = make_int2(((s & 127) << 15) | d, __float_as_int(wn));
    }
}

// L4: batched gather-fold. Group = 32 lanes (lane = class); per iteration the
// group loads 8 consecutive records with ONE dwordx2 (lane sub = base+(c&7)),
// shfl-broadcasts them, then issues 8 independent fc_wT loads + 8 LDS atomics
// (bank = lane -> conflict-free; 2 groups/wave = 2-way = free).
__global__ __launch_bounds__(512) void l4_fold(const int2* __restrict__ erec,
        const int* __restrict__ off, const float* __restrict__ dinv,
        const float* __restrict__ fc_wT, float* __restrict__ g_part) {
    __shared__ float gl[BN * CPAD];   // 16 KB
    int bucket = blockIdx.x, slice = blockIdx.y;
    int nlo = bucket * BN;
    for (int i = threadIdx.x; i < BN * CPAD; i += 512) gl[i] = 0.f;
    __syncthreads();
    int bstart = off[bucket * NSLAB];
    int bend   = off[(bucket + 1) * NSLAB];
    int len = bend - bstart;
    int s0 = bstart + (len * slice) / FSLICE;
    int s1 = bstart + (len * (slice + 1)) / FSLICE;
    int c = threadIdx.x & 31;
    int grp = threadIdx.x >> 5;   // 0..15
    int sub = c & 7;
    for (int base = s0 + grp * 8; base < s1; base += 16 * 8) {
        int idx = base + sub;
        int2 r = (idx < s1) ? erec[idx] : make_int2(0, 0);   // zeros add 0.0
        #pragma unroll
        for (int j = 0; j < 8; j++) {
            int rx = __shfl(r.x, j, 32);
            float wn = __int_as_float(__shfl(r.y, j, 32));
            int d = rx & 0x7FFF;
            int sl = ((unsigned)rx) >> 15;
            atomicAdd(&gl[sl * CPAD + c], wn * fc_wT[d * CPAD + c]);
        }
    }
    if (slice == FSLICE - 1) {   // self-loops
        for (int i = grp; i < BN; i += 16) {
            int n = nlo + i;
            if (n < N_NODES) {
                float di = dinv[n];
                atomicAdd(&gl[i * CPAD + c], di * di * fc_wT[n * CPAD + c]);
            }
        }
    }
    __syncthreads();
    float* outp = g_part + ((size_t)slice * NPB + nlo) * CPAD;
    for (int i = threadIdx.x; i < BN * CPAD; i += 512) outp[i] = gl[i];
}

// L5: logits partials; 4-slice g reduction inlined in the gt stage.
__global__ __launch_bounds__(512) void l5_gemm(const float* __restrict__ x,
        const float* __restrict__ g_part, float* __restrict__ part) {
    __shared__ float xl[(NCHUNK / 2) * XL_LD];   // 32x130 = 16.6 KB
    __shared__ float gt[CPAD * GT_LD];           // 32x68  =  8.7 KB
    int ch = blockIdx.x, bh = blockIdx.y;
    int n0 = ch * NCHUNK;
    int b0 = bh * 64;
    for (int o = threadIdx.x; o < 64 * NCHUNK; o += 512) {
        int b = o >> 6, n = o & (NCHUNK - 1);
        int gn = n0 + n;
        float v = (gn < N_NODES) ? x[(size_t)(b0 + b) * N_NODES + gn] : 0.f;
        xl[(n >> 1) * XL_LD + b * 2 + (n & 1)] = v;
    }
    for (int o = threadIdx.x; o < NCHUNK * CPAD; o += 512) {
        int n = o >> 5, cc = o & 31;
        float s = 0.f;
        #pragma unroll
        for (int sl = 0; sl < FSLICE; sl++)
            s += g_part[((size_t)sl * NPB + n0) * CPAD + o];
        gt[cc * GT_LD + n] = s;
    }
    __syncthreads();
    int wv = threadIdx.x >> 6, l = threadIdx.x & 63;
    float acc0 = 0.f, acc1 = 0.f, acc2 = 0.f, acc3 = 0.f;
    #pragma unroll
    for (int n4 = 0; n4 < NCHUNK / 4; n4++) {
        float2 xa = *(const float2*)&xl[(2 * n4) * XL_LD + l * 2];
        float2 xb = *(const float2*)&xl[(2 * n4 + 1) * XL_LD + l * 2];
        float4 ga = *(const float4*)&gt[(wv)      * GT_LD + 4 * n4];
        float4 gb = *(const float4*)&gt[(wv +  8) * GT_LD + 4 * n4];
        float4 gc = *(const float4*)&gt[(wv + 16) * GT_LD + 4 * n4];
        float4 gd = *(const float4*)&gt[(wv + 24) * GT_LD + 4 * n4];
        acc0 += xa.x * ga.x + xa.y * ga.y + xb.x * ga.z + xb.y * ga.w;
        acc1 += xa.x * gb.x + xa.y * gb.y + xb.x * gb.z + xb.y * gb.w;
        acc2 += xa.x * gc.x + xa.y * gc.y + xb.x * gc.z + xb.y * gc.w;
        acc3 += xa.x * gd.x + xa.y * gd.y + xb.x * gd.z + xb.y * gd.w;
    }
    size_t pb = (size_t)(ch * 2 + bh) * CPAD * 64;
    part[pb + (size_t)(wv)      * 64 + l] = acc0;
    part[pb + (size_t)(wv +  8) * 64 + l] = acc1;
    part[pb + (size_t)(wv + 16) * 64 + l] = acc2;
    part[pb + (size_t)(wv + 24) * 64 + l] = acc3;
}

// L6: partial chunk-reduction (30 classes x 4 quarters)
__global__ __launch_bounds__(128) void l6_lred(const float* __restrict__ part,
        float* __restrict__ lpart) {
    int c = blockIdx.x, q = blockIdx.y;
    int b = threadIdx.x;
    int bhl = b >> 6, l = b & 63;
    float s = 0.f;
    for (int ch = q; ch < NCHUNKS; ch += 4)
        s += part[(((size_t)ch * 2 + bhl) * CPAD + c) * 64 + l];
    lpart[(q * N_CLASSES + c) * 128 + b] = s;
}

// L7: final sum + bias + softmax
__global__ void l7_smax(const float* __restrict__ lpart,
        const float* __restrict__ fc_b, float* __restrict__ out) {
    int b = threadIdx.x;
    float v[N_CLASSES], m = -1e30f;
    #pragma unroll
    for (int c = 0; c < N_CLASSES; c++) {
        float s = fc_b[c];
        #pragma unroll
        for (int q = 0; q < 4; q++) s += lpart[(q * N_CLASSES + c) * 128 + b];
        v[c] = s; m = fmaxf(m, s);
    }
    float s = 0.f;
    #pragma unroll
    for (int c = 0; c < N_CLASSES; c++) { v[c] = __expf(v[c] - m); s += v[c]; }
    float inv = 1.0f / s;
    #pragma unroll
    for (int c = 0; c < N_CLASSES; c++) out[b * N_CLASSES + c] = v[c] * inv;
}

extern "C" void kernel_launch(void* const* d_in, const int* in_sizes, int n_in,
                              void* d_out, int out_size, void* d_ws, size_t ws_size,
                              hipStream_t stream) {
    const float* x          = (const float*)d_in[0];
    const int*   edge_index = (const int*)d_in[1];
    const float* ew         = (const float*)d_in[2];
    const float* fc_w       = (const float*)d_in[3];
    const float* fc_b       = (const float*)d_in[4];
    float* out = (float*)d_out;

    const int* src = edge_index;
    const int* dst = edge_index + N_EDGES_C;

    // ws layout (floats), time-disjoint aliasing:
    //   A (2,572,288): degp [L1..L2] -> g_part [L4..L5]
    //   B (1,282,048): erec [L3..L4] -> part   [L5..L6]
    float* A     = (float*)d_ws;
    float* B     = A + (size_t)FSLICE * NPB * CPAD;          // 2,572,288
    float* dinv  = B + 1282048;                              // 20,000
    int*   cnt   = (int*)(dinv + N_NODES);                   // 40,192
    int*   off   = cnt + NSCAN;                              // 40,193 (pad 40,200)
    float* fc_wT = (float*)(off + 40200);                    // 643,072
    float* lpart = fc_wT + (size_t)NPB * CPAD;               // 15,360

    l1_hists<<<2 * HBLKS + NSLAB, 256, 0, stream>>>(src, dst, ew, A, cnt);
    l2_prep<<<1 + (NPB * CPAD) / 1024 + 20, 1024, 0, stream>>>(cnt, off, fc_w, A,
                                                               fc_wT, dinv);
    l3_scatter<<<NSLAB, 512, 0, stream>>>(src, dst, ew, dinv, off, (int2*)B);
    l4_fold<<<dim3(NBUCKET, FSLICE), 512, 0, stream>>>((int2*)B, off, dinv, fc_wT, A);
    l5_gemm<<<dim3(NCHUNKS, 2), 512, 0, stream>>>(x, A, B);
    l6_lred<<<dim3(N_CLASSES, 4), 128, 0, stream>>>(B, lpart);
    l7_smax<<<1, 128, 0, stream>>>(lpart, fc_b, out);
}

// Round 6
// 188.213 us; speedup vs baseline: 1.4394x; 1.3265x over previous
//
#include <hip/hip_runtime.h>

// DiffuseLR v4: two-level counting sort (bucket, then node within bucket in LDS),
// then register-accumulate CSR gather fold. Zero device atomics, zero LDS
// atomics in the hot fold loop.
//   g[s,c] = sum_{e:src=s} wn_e*fc_w[c,dst_e] + dinv[s]^2*fc_w[c,s]
//   logits = x @ gT + b; out = softmax.

#define N_NODES   20000
#define N_EDGES_C 640000
#define N_CLASSES 30
#define CPAD      32

// deg-hist geometry
#define HBLKS     64
#define HNODES    10000
#define HEDGES    (N_EDGES_C / HBLKS)     // 10000

// partition geometry
#define BN        64                      // nodes per bucket
#define NBUCKET   313                     // ceil(20000/64)
#define NPB       (NBUCKET * BN)          // 20032
#define NSLAB     256
#define SLAB_E    (N_EDGES_C / NSLAB)     // 2500
#define NSCAN     (NBUCKET * NSLAB)       // 80128
#define SCAN_PT   79                      // 1024*79 >= NSCAN+1
#define ECAP      2600                    // per-bucket edge cap (mean 2044, sd 45)

// gemm geometry
#define NCHUNK    64
#define NCHUNKS   313
#define XL_LD     130
#define GT_LD     68

// L1: (a) blocks [0,128): weighted in-degree LDS histogram per (edge-slab, half)
//     (b) blocks [128,384): src-bucket counts per slab (counting-sort pass 1)
__global__ __launch_bounds__(256) void l1_hists(const int* __restrict__ src,
        const int* __restrict__ dst, const float* __restrict__ w,
        float* __restrict__ degp, int* __restrict__ cnt) {
    __shared__ float h[HNODES];   // 40 KB (aliased as int bc[] in role b)
    int bid = blockIdx.x;
    if (bid < 2 * HBLKS) {
        int eb = bid >> 1, half = bid & 1;
        int nbase = half * HNODES;
        for (int i = threadIdx.x; i < HNODES; i += 256) h[i] = 0.f;
        __syncthreads();
        const int4* d4 = (const int4*)(dst + eb * HEDGES);
        const float4* w4 = (const float4*)(w + eb * HEDGES);
        for (int i = threadIdx.x; i < HEDGES / 4; i += 256) {
            int4 dv = d4[i]; float4 wv = w4[i];
            unsigned r;
            r = (unsigned)(dv.x - nbase); if (r < HNODES) atomicAdd(&h[r], wv.x);
            r = (unsigned)(dv.y - nbase); if (r < HNODES) atomicAdd(&h[r], wv.y);
            r = (unsigned)(dv.z - nbase); if (r < HNODES) atomicAdd(&h[r], wv.z);
            r = (unsigned)(dv.w - nbase); if (r < HNODES) atomicAdd(&h[r], wv.w);
        }
        __syncthreads();
        float* outp = degp + (size_t)bid * HNODES;
        for (int i = threadIdx.x; i < HNODES; i += 256) outp[i] = h[i];
    } else {
        int slab = bid - 2 * HBLKS;
        int* bc = (int*)h;
        for (int i = threadIdx.x; i < NBUCKET; i += 256) bc[i] = 0;
        __syncthreads();
        const int4* s4 = (const int4*)(src + slab * SLAB_E);
        for (int i = threadIdx.x; i < SLAB_E / 4; i += 256) {
            int4 v = s4[i];
            atomicAdd(&bc[v.x >> 6], 1);
            atomicAdd(&bc[v.y >> 6], 1);
            atomicAdd(&bc[v.z >> 6], 1);
            atomicAdd(&bc[v.w >> 6], 1);
        }
        __syncthreads();
        for (int b = threadIdx.x; b < NBUCKET; b += 256) cnt[b * NSLAB + slab] = bc[b];
    }
}

// L2: block 0 = exclusive scan cnt->off; blocks [1,626] = fc_w transpose-pad;
//     blocks [627,646] = dinv = rsqrt(1 + deg).
__global__ __launch_bounds__(1024) void l2_prep(const int* __restrict__ cnt,
        int* __restrict__ off, const float* __restrict__ fc_w,
        const float* __restrict__ degp, float* __restrict__ fc_wT,
        float* __restrict__ dinv) {
    int bid = blockIdx.x;
    if (bid == 0) {
        __shared__ int partial[1024];
        int t = threadIdx.x;
        int i0 = t * SCAN_PT;
        int vals[SCAN_PT];
        int sum = 0;
        #pragma unroll
        for (int j = 0; j < SCAN_PT; j++) {
            int i = i0 + j;
            int v = (i < NSCAN) ? cnt[i] : 0;
            vals[j] = v; sum += v;
        }
        partial[t] = sum;
        __syncthreads();
        for (int o = 1; o < 1024; o <<= 1) {
            int v = (t >= o) ? partial[t - o] : 0;
            __syncthreads();
            partial[t] += v;
            __syncthreads();
        }
        int base = (t > 0) ? partial[t - 1] : 0;
        #pragma unroll
        for (int j = 0; j < SCAN_PT; j++) {
            int i = i0 + j;
            if (i <= NSCAN) off[i] = base;
            base += vals[j];
        }
    } else if (bid <= (NPB * CPAD) / 1024) {       // 626 blocks
        int idx = (bid - 1) * 1024 + threadIdx.x;
        int n = idx >> 5, c = idx & 31;
        fc_wT[idx] = (c < N_CLASSES && n < N_NODES) ? fc_w[c * N_NODES + n] : 0.f;
    } else {
        int n = (bid - 1 - (NPB * CPAD) / 1024) * 1024 + threadIdx.x;
        if (n < N_NODES) {
            int half = n / HNODES, nn = n - half * HNODES;
            float s = 1.0f;   // self-loop weight
            for (int eb = 0; eb < HBLKS; eb++)
                s += degp[(size_t)((eb << 1) | half) * HNODES + nn];
            dinv[n] = rsqrtf(s);
        }
    }
}

// L3: scatter edges into bucket-partitioned records {(s_local<<15)|d, wn}
__global__ __launch_bounds__(512) void l3_scatter(const int* __restrict__ src,
        const int* __restrict__ dst, const float* __restrict__ w,
        const float* __restrict__ dinv, const int* __restrict__ off,
        int2* __restrict__ erec) {
    __shared__ int cur[NBUCKET];
    int slab = blockIdx.x;
    for (int b = threadIdx.x; b < NBUCKET; b += 512) cur[b] = off[b * NSLAB + slab];
    __syncthreads();
    int e0 = slab * SLAB_E;
    const int4* s4 = (const int4*)(src + e0);
    const int4* d4 = (const int4*)(dst + e0);
    const float4* w4 = (const float4*)(w + e0);
    for (int i = threadIdx.x; i < SLAB_E / 4; i += 512) {
        int4 sv = s4[i]; int4 dv = d4[i]; float4 wv = w4[i];
        int s, d, p; float wn;
        s = sv.x; d = dv.x; wn = dinv[s] * wv.x * dinv[d];
        p = atomicAdd(&cur[s >> 6], 1);
        erec[p] = make_int2(((s & 63) << 15) | d, __float_as_int(wn));
        s = sv.y; d = dv.y; wn = dinv[s] * wv.y * dinv[d];
        p = atomicAdd(&cur[s >> 6], 1);
        erec[p] = make_int2(((s & 63) << 15) | d, __float_as_int(wn));
        s = sv.z; d = dv.z; wn = dinv[s] * wv.z * dinv[d];
        p = atomicAdd(&cur[s >> 6], 1);
        erec[p] = make_int2(((s & 63) << 15) | d, __float_as_int(wn));
        s = sv.w; d = dv.w; wn = dinv[s] * wv.w * dinv[d];
        p = atomicAdd(&cur[s >> 6], 1);
        erec[p] = make_int2(((s & 63) << 15) | d, __float_as_int(wn));
    }
}

// L4: per-bucket in-LDS counting sort by node, then register-accumulate gather.
// 16 groups of 32 lanes; lane = class. No atomics in the gather loop.
__global__ __launch_bounds__(512) void l4_fold(const int2* __restrict__ erec,
        const int* __restrict__ off, const float* __restrict__ dinv,
        const float* __restrict__ fc_wT, float* __restrict__ gT) {
    __shared__ int2 srt[ECAP];        // 20.8 KB
    __shared__ int hist[BN];
    __shared__ int rowst[BN];
    __shared__ int cur[BN];
    int bucket = blockIdx.x;
    int nlo = bucket * BN;
    int bstart = off[bucket * NSLAB];
    int bend   = off[(bucket + 1) * NSLAB];
    int len = min(bend - bstart, ECAP);
    if (threadIdx.x < BN) hist[threadIdx.x] = 0;
    __syncthreads();
    // pass A: node histogram (tiny LDS atomics)
    for (int i = threadIdx.x; i < len; i += 512)
        atomicAdd(&hist[((unsigned)erec[bstart + i].x) >> 15], 1);
    __syncthreads();
    // wave-scan of 64 counters -> row starts + cursors
    if (threadIdx.x < BN) {
        int h = hist[threadIdx.x];
        int v = h;
        #pragma unroll
        for (int o = 1; o < BN; o <<= 1) {
            int u = __shfl_up(v, o, 64);
            if (threadIdx.x >= o) v += u;
        }
        rowst[threadIdx.x] = v - h;
        cur[threadIdx.x]   = v - h;
    }
    __syncthreads();
    // pass B: scatter into sorted LDS array
    for (int i = threadIdx.x; i < len; i += 512) {
        int2 r = erec[bstart + i];
        int p = atomicAdd(&cur[((unsigned)r.x) >> 15], 1);
        srt[p] = r;
    }
    __syncthreads();
    // gather: group handles nodes grp, grp+16, grp+32, grp+48; lane = class
    int c = threadIdx.x & 31;
    int grp = threadIdx.x >> 5;
    for (int nn = grp; nn < BN; nn += 16) {
        int n = nlo + nn;
        if (n >= N_NODES) { gT[(size_t)n * CPAD + c] = 0.f; continue; }
        float di = dinv[n];
        float acc  = di * di * fc_wT[(size_t)n * CPAD + c];   // self-loop
        float acc2 = 0.f;
        int i = rowst[nn], re = i + hist[nn];
        for (; i + 1 < re; i += 2) {
            int2 r0 = srt[i], r1 = srt[i + 1];                // LDS broadcast
            acc  += __int_as_float(r0.y) * fc_wT[(size_t)(r0.x & 0x7FFF) * CPAD + c];
            acc2 += __int_as_float(r1.y) * fc_wT[(size_t)(r1.x & 0x7FFF) * CPAD + c];
        }
        if (i < re) {
            int2 r0 = srt[i];
            acc += __int_as_float(r0.y) * fc_wT[(size_t)(r0.x & 0x7FFF) * CPAD + c];
        }
        gT[(size_t)n * CPAD + c] = acc + acc2;
    }
}

// L5: logits partials (gT read directly, no slice reduction)
__global__ __launch_bounds__(512) void l5_gemm(const float* __restrict__ x,
        const float* __restrict__ gT, float* __restrict__ part) {
    __shared__ float xl[(NCHUNK / 2) * XL_LD];   // 16.6 KB
    __shared__ float gt[CPAD * GT_LD];           //  8.7 KB
    int ch = blockIdx.x, bh = blockIdx.y;
    int n0 = ch * NCHUNK;
    int b0 = bh * 64;
    for (int o = threadIdx.x; o < 64 * NCHUNK; o += 512) {
        int b = o >> 6, n = o & (NCHUNK - 1);
        int gn = n0 + n;
        float v = (gn < N_NODES) ? x[(size_t)(b0 + b) * N_NODES + gn] : 0.f;
        xl[(n >> 1) * XL_LD + b * 2 + (n & 1)] = v;
    }
    for (int o = threadIdx.x; o < NCHUNK * CPAD; o += 512) {
        int n = o >> 5, cc = o & 31;
        gt[cc * GT_LD + n] = gT[(size_t)n0 * CPAD + o];
    }
    __syncthreads();
    int wv = threadIdx.x >> 6, l = threadIdx.x & 63;
    float acc0 = 0.f, acc1 = 0.f, acc2 = 0.f, acc3 = 0.f;
    #pragma unroll
    for (int n4 = 0; n4 < NCHUNK / 4; n4++) {
        float2 xa = *(const float2*)&xl[(2 * n4) * XL_LD + l * 2];
        float2 xb = *(const float2*)&xl[(2 * n4 + 1) * XL_LD + l * 2];
        float4 ga = *(const float4*)&gt[(wv)      * GT_LD + 4 * n4];
        float4 gb = *(const float4*)&gt[(wv +  8) * GT_LD + 4 * n4];
        float4 gc = *(const float4*)&gt[(wv + 16) * GT_LD + 4 * n4];
        float4 gd = *(const float4*)&gt[(wv + 24) * GT_LD + 4 * n4];
        acc0 += xa.x * ga.x + xa.y * ga.y + xb.x * ga.z + xb.y * ga.w;
        acc1 += xa.x * gb.x + xa.y * gb.y + xb.x * gb.z + xb.y * gb.w;
        acc2 += xa.x * gc.x + xa.y * gc.y + xb.x * gc.z + xb.y * gc.w;
        acc3 += xa.x * gd.x + xa.y * gd.y + xb.x * gd.z + xb.y * gd.w;
    }
    size_t pb = (size_t)(ch * 2 + bh) * CPAD * 64;
    part[pb + (size_t)(wv)      * 64 + l] = acc0;
    part[pb + (size_t)(wv +  8) * 64 + l] = acc1;
    part[pb + (size_t)(wv + 16) * 64 + l] = acc2;
    part[pb + (size_t)(wv + 24) * 64 + l] = acc3;
}

// L6: partial chunk-reduction (30 classes x 4 quarters)
__global__ __launch_bounds__(128) void l6_lred(const float* __restrict__ part,
        float* __restrict__ lpart) {
    int c = blockIdx.x, q = blockIdx.y;
    int b = threadIdx.x;
    int bhl = b >> 6, l = b & 63;
    float s = 0.f;
    for (int ch = q; ch < NCHUNKS; ch += 4)
        s += part[(((size_t)ch * 2 + bhl) * CPAD + c) * 64 + l];
    lpart[(q * N_CLASSES + c) * 128 + b] = s;
}

// L7: final sum + bias + softmax
__global__ void l7_smax(const float* __restrict__ lpart,
        const float* __restrict__ fc_b, float* __restrict__ out) {
    int b = threadIdx.x;
    float v[N_CLASSES], m = -1e30f;
    #pragma unroll
    for (int c = 0; c < N_CLASSES; c++) {
        float s = fc_b[c];
        #pragma unroll
        for (int q = 0; q < 4; q++) s += lpart[(q * N_CLASSES + c) * 128 + b];
        v[c] = s; m = fmaxf(m, s);
    }
    float s = 0.f;
    #pragma unroll
    for (int c = 0; c < N_CLASSES; c++) { v[c] = __expf(v[c] - m); s += v[c]; }
    float inv = 1.0f / s;
    #pragma unroll
    for (int c = 0; c < N_CLASSES; c++) out[b * N_CLASSES + c] = v[c] * inv;
}

extern "C" void kernel_launch(void* const* d_in, const int* in_sizes, int n_in,
                              void* d_out, int out_size, void* d_ws, size_t ws_size,
                              hipStream_t stream) {
    const float* x          = (const float*)d_in[0];
    const int*   edge_index = (const int*)d_in[1];
    const float* ew         = (const float*)d_in[2];
    const float* fc_w       = (const float*)d_in[3];
    const float* fc_b       = (const float*)d_in[4];
    float* out = (float*)d_out;

    const int* src = edge_index;
    const int* dst = edge_index + N_EDGES_C;

    // ws layout (float slots), time-disjoint aliasing:
    //   A (1,282,048): degp [L1..L2] -> part [L5..L6]
    //   B (1,280,000): erec [L3..L4]
    float* A     = (float*)d_ws;                             // 1,282,048
    float* B     = A + 1282048;                              // 1,280,000
    float* dinv  = B + 1280000;                              // 20,000
    int*   cnt   = (int*)(dinv + N_NODES);                   // 80,128
    int*   off   = cnt + NSCAN;                              // 80,136 (padded)
    float* fc_wT = (float*)(off + 80136);                    // 641,024
    float* gT    = fc_wT + (size_t)NPB * CPAD;               // 641,024
    float* lpart = gT + (size_t)NPB * CPAD;                  // 15,360

    l1_hists<<<2 * HBLKS + NSLAB, 256, 0, stream>>>(src, dst, ew, A, cnt);
    l2_prep<<<1 + (NPB * CPAD) / 1024 + 20, 1024, 0, stream>>>(cnt, off, fc_w, A,
                                                               fc_wT, dinv);
    l3_scatter<<<NSLAB, 512, 0, stream>>>(src, dst, ew, dinv, off, (int2*)B);
    l4_fold<<<NBUCKET, 512, 0, stream>>>((int2*)B, off, dinv, fc_wT, gT);
    l5_gemm<<<dim3(NCHUNKS, 2), 512, 0, stream>>>(x, gT, A);
    l6_lred<<<dim3(N_CLASSES, 4), 128, 0, stream>>>(A, lpart);
    l7_smax<<<1, 128, 0, stream>>>(lpart, fc_b, out);
}

// Round 7
// 101.248 us; speedup vs baseline: 2.6757x; 1.8589x over previous
//
#include <hip/hip_runtime.h>

// DiffuseLR v5: two-level counting sort (bucket, then node-in-bucket in LDS) +
// register-accumulate gather fold + split GEMM. Zero device atomics.
// Hierarchical offset scan (no per-thread arrays -> no scratch spill).
//   g[s,c] = sum_{e:src=s} wn_e*fc_w[c,dst_e] + dinv[s]^2*fc_w[c,s]
//   logits = x @ gT + b; out = softmax.

#define N_NODES   20000
#define N_EDGES_C 640000
#define N_CLASSES 30
#define CPAD      32

// deg-hist geometry
#define HBLKS     64
#define HNODES    10000
#define HEDGES    (N_EDGES_C / HBLKS)     // 10000

// partition geometry
#define BN        64                      // nodes per bucket
#define NBUCKET   313                     // ceil(20000/64)
#define NPB       (NBUCKET * BN)          // 20032
#define NSLAB     256
#define SLAB_E    (N_EDGES_C / NSLAB)     // 2500
#define NSCAN     (NBUCKET * NSLAB)       // 80128
#define ECAP      2600                    // per-bucket cap (mean 2044, sd ~45)

// gemm geometry
#define NCHUNK    64
#define NCHUNKS   313
#define XL_LD     130
#define GT_LD     68

#define FCB       ((NPB * CPAD) / 256)    // 2504 transpose blocks
#define DINVB     ((N_NODES + 255) / 256) // 79

// K1: (a) blocks [0,128): weighted in-degree LDS histogram per (edge-slab, half)
//     (b) blocks [128,384): src-bucket counts per slab (counting-sort pass 1)
__global__ __launch_bounds__(256) void k1_hists(const int* __restrict__ src,
        const int* __restrict__ dst, const float* __restrict__ w,
        float* __restrict__ degp, int* __restrict__ cnt) {
    __shared__ float h[HNODES];   // 40 KB (aliased as int bc[] in role b)
    int bid = blockIdx.x;
    if (bid < 2 * HBLKS) {
        int eb = bid >> 1, half = bid & 1;
        int nbase = half * HNODES;
        for (int i = threadIdx.x; i < HNODES; i += 256) h[i] = 0.f;
        __syncthreads();
        const int4* d4 = (const int4*)(dst + eb * HEDGES);
        const float4* w4 = (const float4*)(w + eb * HEDGES);
        for (int i = threadIdx.x; i < HEDGES / 4; i += 256) {
            int4 dv = d4[i]; float4 wv = w4[i];
            unsigned r;
            r = (unsigned)(dv.x - nbase); if (r < HNODES) atomicAdd(&h[r], wv.x);
            r = (unsigned)(dv.y - nbase); if (r < HNODES) atomicAdd(&h[r], wv.y);
            r = (unsigned)(dv.z - nbase); if (r < HNODES) atomicAdd(&h[r], wv.z);
            r = (unsigned)(dv.w - nbase); if (r < HNODES) atomicAdd(&h[r], wv.w);
        }
        __syncthreads();
        float* outp = degp + (size_t)bid * HNODES;
        for (int i = threadIdx.x; i < HNODES; i += 256) outp[i] = h[i];
    } else {
        int slab = bid - 2 * HBLKS;
        int* bc = (int*)h;
        for (int i = threadIdx.x; i < NBUCKET; i += 256) bc[i] = 0;
        __syncthreads();
        const int4* s4 = (const int4*)(src + slab * SLAB_E);
        for (int i = threadIdx.x; i < SLAB_E / 4; i += 256) {
            int4 v = s4[i];
            atomicAdd(&bc[v.x >> 6], 1);
            atomicAdd(&bc[v.y >> 6], 1);
            atomicAdd(&bc[v.z >> 6], 1);
            atomicAdd(&bc[v.w >> 6], 1);
        }
        __syncthreads();
        for (int b = threadIdx.x; b < NBUCKET; b += 256) cnt[b * NSLAB + slab] = bc[b];
    }
}

// K2: (a) blocks [0,313): btot[b] = sum_slab cnt[b][slab]
//     (b) blocks [313,313+2504): fc_w transpose-pad
//     (c) blocks [..+79): dinv = rsqrt(1 + deg)
__global__ __launch_bounds__(256) void k2_prep(const int* __restrict__ cnt,
        int* __restrict__ btot, const float* __restrict__ fc_w,
        const float* __restrict__ degp, float* __restrict__ fc_wT,
        float* __restrict__ dinv) {
    int bid = blockIdx.x;
    if (bid < NBUCKET) {
        __shared__ int lds[256];
        int t = threadIdx.x;
        lds[t] = cnt[bid * NSLAB + t];
        __syncthreads();
        for (int o = 128; o > 0; o >>= 1) {
            if (t < o) lds[t] += lds[t + o];
            __syncthreads();
        }
        if (t == 0) btot[bid] = lds[0];
    } else if (bid < NBUCKET + FCB) {
        int idx = (bid - NBUCKET) * 256 + threadIdx.x;
        int n = idx >> 5, c = idx & 31;
        fc_wT[idx] = (c < N_CLASSES && n < N_NODES) ? fc_w[c * N_NODES + n] : 0.f;
    } else {
        int n = (bid - NBUCKET - FCB) * 256 + threadIdx.x;
        if (n < N_NODES) {
            int half = n / HNODES, nn = n - half * HNODES;
            float s = 1.0f;   // self-loop weight
            for (int eb = 0; eb < HBLKS; eb++)
                s += degp[(size_t)((eb << 1) | half) * HNODES + nn];
            dinv[n] = rsqrtf(s);
        }
    }
}

// K3: per-bucket offsets. Block b: bbase = sum_{b'<b} btot[b'] (strided reduce),
// then 256-wide LDS scan of cnt[b][*] -> off[b*NSLAB+slab] = bbase + excl-prefix.
__global__ __launch_bounds__(256) void k3_off(const int* __restrict__ cnt,
        const int* __restrict__ btot, int* __restrict__ off) {
    __shared__ int lds[256];
    __shared__ int bb;
    int b = blockIdx.x, t = threadIdx.x;
    int s = 0;
    for (int i = t; i < b; i += 256) s += btot[i];
    lds[t] = s;
    __syncthreads();
    for (int o = 128; o > 0; o >>= 1) {
        if (t < o) lds[t] += lds[t + o];
        __syncthreads();
    }
    if (t == 0) bb = lds[0];
    __syncthreads();
    int base = bb;
    int v = cnt[b * NSLAB + t];
    lds[t] = v;
    __syncthreads();
    for (int o = 1; o < 256; o <<= 1) {
        int u = (t >= o) ? lds[t - o] : 0;
        __syncthreads();
        lds[t] += u;
        __syncthreads();
    }
    off[b * NSLAB + t] = base + lds[t] - v;          // exclusive prefix
    if (b == NBUCKET - 1 && t == 255) off[NSCAN] = base + lds[t];
}

// K4: scatter edges into bucket-partitioned records {(s_local<<15)|d, wn}
__global__ __launch_bounds__(512) void k4_scatter(const int* __restrict__ src,
        const int* __restrict__ dst, const float* __restrict__ w,
        const float* __restrict__ dinv, const int* __restrict__ off,
        int2* __restrict__ erec) {
    __shared__ int cur[NBUCKET];
    int slab = blockIdx.x;
    for (int b = threadIdx.x; b < NBUCKET; b += 512) cur[b] = off[b * NSLAB + slab];
    __syncthreads();
    int e0 = slab * SLAB_E;
    const int4* s4 = (const int4*)(src + e0);
    const int4* d4 = (const int4*)(dst + e0);
    const float4* w4 = (const float4*)(w + e0);
    for (int i = threadIdx.x; i < SLAB_E / 4; i += 512) {
        int4 sv = s4[i]; int4 dv = d4[i]; float4 wv = w4[i];
        int s, d, p; float wn;
        s = sv.x; d = dv.x; wn = dinv[s] * wv.x * dinv[d];
        p = atomicAdd(&cur[s >> 6], 1);
        erec[p] = make_int2(((s & 63) << 15) | d, __float_as_int(wn));
        s = sv.y; d = dv.y; wn = dinv[s] * wv.y * dinv[d];
        p = atomicAdd(&cur[s >> 6], 1);
        erec[p] = make_int2(((s & 63) << 15) | d, __float_as_int(wn));
        s = sv.z; d = dv.z; wn = dinv[s] * wv.z * dinv[d];
        p = atomicAdd(&cur[s >> 6], 1);
        erec[p] = make_int2(((s & 63) << 15) | d, __float_as_int(wn));
        s = sv.w; d = dv.w; wn = dinv[s] * wv.w * dinv[d];
        p = atomicAdd(&cur[s >> 6], 1);
        erec[p] = make_int2(((s & 63) << 15) | d, __float_as_int(wn));
    }
}

// K5: per-bucket in-LDS counting sort by node, then register-accumulate gather.
__global__ __launch_bounds__(512) void k5_fold(const int2* __restrict__ erec,
        const int* __restrict__ off, const float* __restrict__ dinv,
        const float* __restrict__ fc_wT, float* __restrict__ gT) {
    __shared__ int2 srt[ECAP];        // 20.8 KB
    __shared__ int hist[BN];
    __shared__ int rowst[BN];
    __shared__ int cur[BN];
    int bucket = blockIdx.x;
    int nlo = bucket * BN;
    int bstart = off[bucket * NSLAB];
    int bend   = off[(bucket + 1) * NSLAB];
    int len = min(bend - bstart, ECAP);
    if (threadIdx.x < BN) hist[threadIdx.x] = 0;
    __syncthreads();
    for (int i = threadIdx.x; i < len; i += 512)
        atomicAdd(&hist[((unsigned)erec[bstart + i].x) >> 15], 1);
    __syncthreads();
    if (threadIdx.x < BN) {
        int h = hist[threadIdx.x];
        int v = h;
        #pragma unroll
        for (int o = 1; o < BN; o <<= 1) {
            int u = __shfl_up(v, o, 64);
            if (threadIdx.x >= o) v += u;
        }
        rowst[threadIdx.x] = v - h;
        cur[threadIdx.x]   = v - h;
    }
    __syncthreads();
    for (int i = threadIdx.x; i < len; i += 512) {
        int2 r = erec[bstart + i];
        int p = atomicAdd(&cur[((unsigned)r.x) >> 15], 1);
        srt[p] = r;
    }
    __syncthreads();
    int c = threadIdx.x & 31;
    int grp = threadIdx.x >> 5;
    for (int nn = grp; nn < BN; nn += 16) {
        int n = nlo + nn;
        if (n >= N_NODES) { gT[(size_t)n * CPAD + c] = 0.f; continue; }
        float di = dinv[n];
        float acc  = di * di * fc_wT[(size_t)n * CPAD + c];   // self-loop
        float acc2 = 0.f;
        int i = rowst[nn], re = i + hist[nn];
        for (; i + 1 < re; i += 2) {
            int2 r0 = srt[i], r1 = srt[i + 1];                // LDS broadcast
            acc  += __int_as_float(r0.y) * fc_wT[(size_t)(r0.x & 0x7FFF) * CPAD + c];
            acc2 += __int_as_float(r1.y) * fc_wT[(size_t)(r1.x & 0x7FFF) * CPAD + c];
        }
        if (i < re) {
            int2 r0 = srt[i];
            acc += __int_as_float(r0.y) * fc_wT[(size_t)(r0.x & 0x7FFF) * CPAD + c];
        }
        gT[(size_t)n * CPAD + c] = acc + acc2;
    }
}

// K6: logits partials
__global__ __launch_bounds__(512) void k6_gemm(const float* __restrict__ x,
        const float* __restrict__ gT, float* __restrict__ part) {
    __shared__ float xl[(NCHUNK / 2) * XL_LD];   // 16.6 KB
    __shared__ float gt[CPAD * GT_LD];           //  8.7 KB
    int ch = blockIdx.x, bh = blockIdx.y;
    int n0 = ch * NCHUNK;
    int b0 = bh * 64;
    for (int o = threadIdx.x; o < 64 * NCHUNK; o += 512) {
        int b = o >> 6, n = o & (NCHUNK - 1);
        int gn = n0 + n;
        float v = (gn < N_NODES) ? x[(size_t)(b0 + b) * N_NODES + gn] : 0.f;
        xl[(n >> 1) * XL_LD + b * 2 + (n & 1)] = v;
    }
    for (int o = threadIdx.x; o < NCHUNK * CPAD; o += 512) {
        int n = o >> 5, cc = o & 31;
        gt[cc * GT_LD + n] = gT[(size_t)n0 * CPAD + o];
    }
    __syncthreads();
    int wv = threadIdx.x >> 6, l = threadIdx.x & 63;
    float acc0 = 0.f, acc1 = 0.f, acc2 = 0.f, acc3 = 0.f;
    #pragma unroll
    for (int n4 = 0; n4 < NCHUNK / 4; n4++) {
        float2 xa = *(const float2*)&xl[(2 * n4) * XL_LD + l * 2];
        float2 xb = *(const float2*)&xl[(2 * n4 + 1) * XL_LD + l * 2];
        float4 ga = *(const float4*)&gt[(wv)      * GT_LD + 4 * n4];
        float4 gb = *(const float4*)&gt[(wv +  8) * GT_LD + 4 * n4];
        float4 gc = *(const float4*)&gt[(wv + 16) * GT_LD + 4 * n4];
        float4 gd = *(const float4*)&gt[(wv + 24) * GT_LD + 4 * n4];
        acc0 += xa.x * ga.x + xa.y * ga.y + xb.x * ga.z + xb.y * ga.w;
        acc1 += xa.x * gb.x + xa.y * gb.y + xb.x * gb.z + xb.y * gb.w;
        acc2 += xa.x * gc.x + xa.y * gc.y + xb.x * gc.z + xb.y * gc.w;
        acc3 += xa.x * gd.x + xa.y * gd.y + xb.x * gd.z + xb.y * gd.w;
    }
    size_t pb = (size_t)(ch * 2 + bh) * CPAD * 64;
    part[pb + (size_t)(wv)      * 64 + l] = acc0;
    part[pb + (size_t)(wv +  8) * 64 + l] = acc1;
    part[pb + (size_t)(wv + 16) * 64 + l] = acc2;
    part[pb + (size_t)(wv + 24) * 64 + l] = acc3;
}

// K7: partial chunk-reduction (30 classes x 4 quarters)
__global__ __launch_bounds__(128) void k7_lred(const float* __restrict__ part,
        float* __restrict__ lpart) {
    int c = blockIdx.x, q = blockIdx.y;
    int b = threadIdx.x;
    int bhl = b >> 6, l = b & 63;
    float s = 0.f;
    for (int ch = q; ch < NCHUNKS; ch += 4)
        s += part[(((size_t)ch * 2 + bhl) * CPAD + c) * 64 + l];
    lpart[(q * N_CLASSES + c) * 128 + b] = s;
}

// K8: final sum + bias + softmax
__global__ void k8_smax(const float* __restrict__ lpart,
        const float* __restrict__ fc_b, float* __restrict__ out) {
    int b = threadIdx.x;
    float v[N_CLASSES], m = -1e30f;
    #pragma unroll
    for (int c = 0; c < N_CLASSES; c++) {
        float s = fc_b[c];
        #pragma unroll
        for (int q = 0; q < 4; q++) s += lpart[(q * N_CLASSES + c) * 128 + b];
        v[c] = s; m = fmaxf(m, s);
    }
    float s = 0.f;
    #pragma unroll
    for (int c = 0; c < N_CLASSES; c++) { v[c] = __expf(v[c] - m); s += v[c]; }
    float inv = 1.0f / s;
    #pragma unroll
    for (int c = 0; c < N_CLASSES; c++) out[b * N_CLASSES + c] = v[c] * inv;
}

extern "C" void kernel_launch(void* const* d_in, const int* in_sizes, int n_in,
                              void* d_out, int out_size, void* d_ws, size_t ws_size,
                              hipStream_t stream) {
    const float* x          = (const float*)d_in[0];
    const int*   edge_index = (const int*)d_in[1];
    const float* ew         = (const float*)d_in[2];
    const float* fc_w       = (const float*)d_in[3];
    const float* fc_b       = (const float*)d_in[4];
    float* out = (float*)d_out;

    const int* src = edge_index;
    const int* dst = edge_index + N_EDGES_C;

    // ws layout (float slots), time-disjoint aliasing:
    //   A (1,282,048): degp [K1..K2] -> part [K6..K7]
    //   B (1,280,000): erec [K4..K5]
    float* A     = (float*)d_ws;                             // 1,282,048
    float* B     = A + 1282048;                              // 1,280,000
    float* dinv  = B + 1280000;                              // 20,000
    int*   cnt   = (int*)(dinv + N_NODES);                   // 80,128
    int*   off   = cnt + NSCAN;                              // 80,129 (pad 80,136)
    int*   btot  = off + 80136;                              // 313 (pad 320)
    float* fc_wT = (float*)(btot + 320);                     // 641,024
    float* gT    = fc_wT + (size_t)NPB * CPAD;               // 641,024
    float* lpart = gT + (size_t)NPB * CPAD;                  // 15,360

    k1_hists<<<2 * HBLKS + NSLAB, 256, 0, stream>>>(src, dst, ew, A, cnt);
    k2_prep<<<NBUCKET + FCB + DINVB, 256, 0, stream>>>(cnt, btot, fc_w, A,
                                                       fc_wT, dinv);
    k3_off<<<NBUCKET, 256, 0, stream>>>(cnt, btot, off);
    k4_scatter<<<NSLAB, 512, 0, stream>>>(src, dst, ew, dinv, off, (int2*)B);
    k5_fold<<<NBUCKET, 512, 0, stream>>>((int2*)B, off, dinv, fc_wT, gT);
    k6_gemm<<<dim3(NCHUNKS, 2), 512, 0, stream>>>(x, gT, A);
    k7_lred<<<dim3(N_CLASSES, 4), 128, 0, stream>>>(A, lpart);
    k8_smax<<<1, 128, 0, stream>>>(lpart, fc_b, out);
}